// Round 20
// baseline (53.431 us; speedup 1.0000x reference)
//
#include <hip/hip_runtime.h>
#include <math.h>

// ---------------------------------------------------------------------------
// ScatteringNetwork — fused, rank-2 composed conv + theta-symmetry
// (R15/R17/R18/R19 base). R20: s2-path strip ALSO bf16-packed (2 adjacent
// cols per u32) -> LDS 49.5 -> 40.0 KB -> 4 blocks/CU (32 waves/CU).
//
// All interior tensors bf16-packed in u32 (strip: col2i|col2i+1, Iv: re|im,
// s1: chanA|chanB; degenerate sources store (v,v)); C per-source 6 fp32
// planes. Weights SGPR (s_load).
//
// psi_k = F_k (x) H_k (rank-1). theta = pi*k/5 -> H3=H2, F3=conj(F2) (pairs
// (1,4),(2,3),(6,9),(7,8); k0,k5 real-H):
//  - s1 pair blocks: both channels from 4 shared real convs
//  - C: conj-trick -> 6 distinct planes {0,1,2,5,6,7}
//  - out: u=H'r*Cr, v=H'i*Ci -> out_k=u-v, out_partner=u+v
// Grid y: 7 = img, g0, g5, pair(1,4), pair(2,3), pair(6,9), pair(7,8).
//
// ws: [0) fhp 10*136 floats only.
// fhp per ch: [0)H'r [17)H'i [34)H''r [51)H''i [68)F'r [85)F'i [102)F''r [119)F''i
// ---------------------------------------------------------------------------

#define W1    298            // packed s1 row stride (u32 slots, 17 rows)
#define SSTRW 140            // packed strip row stride (u32 word slots, 27 rows)
#define IVSTR 299            // packed Iv row stride (u32 slots, 17 rows)
#define CSTR  600            // C fp32 per-plane stride (re@0, im@300), 6 planes

static __device__ __forceinline__ unsigned packbf2(float a, float b) {
    unsigned ua = __float_as_uint(a);
    unsigned ub = __float_as_uint(b);
    ua = (ua + 0x7FFFu + ((ua >> 16) & 1u)) >> 16;          // RNE bf16, lo
    ub = (ub + 0x7FFFu + ((ub >> 16) & 1u)) & 0xFFFF0000u;  // RNE bf16, hi
    return ua | ub;
}
static __device__ __forceinline__ float unplo(unsigned u) { return __uint_as_float(u << 16); }
static __device__ __forceinline__ float unphi(unsigned u) { return __uint_as_float(u & 0xFFFF0000u); }

// ---------------- k_fhp: composed factor table only (tiny) -----------------
__global__ void k_fhp(const float* __restrict__ psi_re,
                      const float* __restrict__ psi_im,
                      const float* __restrict__ blur,
                      float* __restrict__ fhp) {
    int g = blockIdx.x * 64 + threadIdx.x;
    if (g >= 1360) return;
    int ch = g / 136;
    int w = g - ch * 136;
    int part = w / 17;
    int i = w - part * 17;
    const float* pr = psi_re + ch * 121;
    const float* pi = psi_im + ch * 121;
    float val = 0.f;
    if (part < 4) {                       // H-type: H_j = psi[5][j]
        int qmin = (part >= 2) ? 3 : 0;
        int comp = part & 1;
        float bden = blur[24];
        for (int q = qmin; q < 7; ++q) {
            int jj = i - q;
            if (jj < 0 || jj > 10) continue;
            float bq = blur[21 + q] / bden;
            float hh = comp ? pi[55 + jj] : pr[55 + jj];
            val += bq * hh;
        }
    } else {                              // F-type: F_i = psi[i][5]/psi[5][5]
        int pmin = (part >= 6) ? 3 : 0;
        int comp = part & 1;
        float dr = pr[60], di = pi[60];
        float inv = 1.f / (dr * dr + di * di);
        for (int p = pmin; p < 7; ++p) {
            int ii = i - p;
            if (ii < 0 || ii > 10) continue;
            float ap = blur[p * 7 + 3];
            float nr = pr[ii * 11 + 5], ni = pi[ii * 11 + 5];
            float f = comp ? (ni * dr - nr * di) * inv
                           : (nr * dr + ni * di) * inv;
            val += ap * f;
        }
    }
    fhp[g] = val;
}

// ---------------- k_fused6: one block per (Y, src2, n), 512 thr ------------
__global__ __launch_bounds__(512, 6) void k_fused6(const float* __restrict__ img,
                                                   const float* __restrict__ psi_re,
                                                   const float* __restrict__ psi_im,
                                                   const float* __restrict__ blur,
                                                   const float* __restrict__ fhp,
                                                   float* __restrict__ out) {
    __shared__ __align__(16) unsigned bufA[5066];  // packed strip [27][140] / packed s1 [17][298]
    __shared__ __align__(16) unsigned bufB[5083];  // packed Iv [17][299] / C fp32 6*600
    unsigned* s1P = bufA;
    unsigned* stripP = bufA;
    unsigned* ivP = bufB;
    float* cbuf = (float*)bufB;
    const int tid = threadIdx.x;
    const int lane = tid & 63;
    const int wave = tid >> 6;
    const int Y = blockIdx.x;
    const int src2 = blockIdx.y;    // 0 img, 1 g0, 2 g5, 3..6 pairs
    const int n = blockIdx.z;
    size_t nb = (size_t)n * 111 * 1024;
    const float* im = img + n * 65536;

    const bool isimg = (src2 == 0);
    const bool paired = (src2 >= 3);
    int ga = 0, gb = 0;
    if (src2 == 1) ga = gb = 0;
    else if (src2 == 2) ga = gb = 5;
    else if (paired) {
        int p2 = src2 - 3;
        ga = (p2 < 2) ? 1 + p2 : 4 + p2;      // 1,2,6,7
        gb = (p2 < 2) ? 4 - p2 : 11 - p2;     // 4,3,9,8
    }

    if (isimg) {
        // stage img strip [17 rows] packed (v,v) into W1 layout, direct from
        // img with predicates. cols cc>264 zeroed (alias row r+1 t0..6 slots).
        int rb = 8 * Y - 8;
        for (int idx = tid; idx < 17 * 68; idx += 512) {
            int r = idx / 68, c4 = idx - r * 68;
            int gr = rb + r;
            float4 v = {0.f, 0.f, 0.f, 0.f};
            if (gr >= 0 && gr < 256 && c4 >= 2 && c4 <= 65)
                v = *(const float4*)(im + gr * 256 + 4 * c4 - 8);
            int c = 4 * c4;
            int d = r * W1 + c + (c >> 3);   // (c>>3) constant within a float4
            float vs[4] = {v.x, v.y, v.z, v.w};
#pragma unroll
            for (int e = 0; e < 4; ++e) {
                float val = (c + e > 264) ? 0.f : vs[e];
                s1P[d + e] = packbf2(val, val);
            }
        }
    } else {
        const float* pr = psi_re + ga * 121;   // block-uniform -> s_load
        const float* pi = psi_im + ga * 121;
        float dr = pr[60], di = pi[60];
        float inv = rsqrtf(dr * dr + di * di);

        // stage packed strip [27][140 words]: img rows 8Y-13.., strip col
        // cc = img col + 8; word cc>>1 holds (cc_even | cc_odd)
        int rb2 = 8 * Y - 13;
        for (int idx = tid; idx < 27 * 68; idx += 512) {
            int r = idx / 68, c4 = idx - r * 68;
            int gr = rb2 + r;
            float4 v = {0.f, 0.f, 0.f, 0.f};
            if (gr >= 0 && gr < 256 && c4 >= 2 && c4 <= 65)
                v = *(const float4*)(im + gr * 256 + 4 * c4 - 8);
            uint2 pw;
            pw.x = packbf2(v.x, v.y);
            pw.y = packbf2(v.z, v.w);
            *(uint2*)(stripP + r * SSTRW + 2 * c4) = pw;
        }
        __syncthreads();

        // Iv packed (re|im): lane = col v, 8 rows/task; strip col v+3 ->
        // word (v+3)>>1, half (v+3)&1 (lanes pair on words -> broadcast)
        for (int task = tid; task < 532; task += 512) {
            int rg = (task >= 266) ? 1 : 0;
            int v = task - rg * 266;
            int r0 = rg * 8;
            const unsigned* sp = stripP + r0 * SSTRW + ((v + 3) >> 1);
            unsigned sh = ((v + 3) & 1) ? 0u : 16u;
            float xv[18];
#pragma unroll
            for (int p = 0; p < 18; ++p) {
                unsigned u = sp[p * SSTRW];
                xv[p] = __uint_as_float((u << sh) & 0xFFFF0000u);
            }
            int dsw = v + (v >> 3);
            unsigned* dP = ivP + r0 * IVSTR + dsw;
#pragma unroll
            for (int m = 0; m < 8; ++m) {
                float ar = 0.f, ai = 0.f;
#pragma unroll
                for (int p = 0; p < 11; ++p) {
                    ar = fmaf(pr[p * 11 + 5], xv[m + p], ar);
                    ai = fmaf(pi[p * 11 + 5], xv[m + p], ai);
                }
                dP[m * IVSTR] = packbf2(ar, ai);
            }
        }
        if (tid < 266) {                     // row 16
            int v = tid;
            const unsigned* sp = stripP + 16 * SSTRW + ((v + 3) >> 1);
            unsigned sh = ((v + 3) & 1) ? 0u : 16u;
            float ar = 0.f, ai = 0.f;
#pragma unroll
            for (int p = 0; p < 11; ++p) {
                unsigned u = sp[p * SSTRW];
                float x = __uint_as_float((u << sh) & 0xFFFF0000u);
                ar = fmaf(pr[p * 11 + 5], x, ar);
                ai = fmaf(pi[p * 11 + 5], x, ai);
            }
            ivP[16 * IVSTR + v + (v >> 3)] = packbf2(ar, ai);
        }
        __syncthreads();

        // s1 packed (chanA|chanB): 18 packed reads -> 36 values
        int rowbase = 8 * Y - 8;
        for (int t2 = tid; t2 < 544; t2 += 512) {
            int r = t2 >> 5, xg = t2 & 31;
            int ry = rowbase + r;
            int wb = r * W1 + 9 * xg + 9;
            if (ry >= 0 && ry < 256) {
                const unsigned* sP = ivP + r * IVSTR + 9 * xg;
                float xr[18], xi[18];
#pragma unroll
                for (int j = 0; j < 18; ++j) {
                    unsigned u = sP[j + (j >> 3)];
                    xr[j] = unplo(u);
                    xi[j] = unphi(u);
                }
                if (paired) {
#pragma unroll
                    for (int m = 0; m < 8; ++m) {
                        float a = 0.f, b = 0.f, c = 0.f, d = 0.f;
#pragma unroll
                        for (int j = 0; j < 11; ++j) {
                            float hr = pr[55 + j], hi2 = pi[55 + j];
                            a = fmaf(hr, xr[m + j], a);
                            b = fmaf(hi2, xi[m + j], b);
                            c = fmaf(hr, xi[m + j], c);
                            d = fmaf(hi2, xr[m + j], d);
                        }
                        float e1 = a - b, o1 = c + d;
                        float e2 = a + b, o2 = c - d;
                        s1P[wb + m] = packbf2(inv * sqrtf(fmaf(e1, e1, o1 * o1)),
                                              inv * sqrtf(fmaf(e2, e2, o2 * o2)));
                    }
                } else {
#pragma unroll
                    for (int m = 0; m < 8; ++m) {
                        float sr = 0.f, si = 0.f;
#pragma unroll
                        for (int j = 0; j < 11; ++j) {
                            float hr = pr[55 + j], hi2 = pi[55 + j];
                            sr = fmaf(hr, xr[m + j], fmaf(-hi2, xi[m + j], sr));
                            si = fmaf(hr, xi[m + j], fmaf(hi2, xr[m + j], si));
                        }
                        float val = inv * sqrtf(fmaf(sr, sr, si * si));
                        s1P[wb + m] = packbf2(val, val);
                    }
                }
            } else {
#pragma unroll
                for (int m = 0; m < 8; ++m) s1P[wb + m] = 0u;
            }
        }
        if (tid < 17) {                      // edge zeros: t 0..7 and t 264 slot
            int r = tid;
#pragma unroll
            for (int t = 0; t < 8; ++t) s1P[r * W1 + t] = 0u;
            s1P[r * W1 + 297] = 0u;
        }
    }
    __syncthreads();

    // ---- per-source: C (6 planes fp32, overwrites Iv) then out ----
    const int nsrc = paired ? 2 : 1;
    for (int sh = 0; sh < nsrc; ++sh) {
        {
            int kh = __builtin_amdgcn_readfirstlane(wave >> 2);   // plane half
            int wl = wave & 3;
            int fro = (Y == 0) ? 102 : 68;
            int fio = (Y == 0) ? 119 : 85;
            {   // main pass: t 0..255
                int t = (wl << 6) + lane;
                int tsw = t + (t >> 3);
                float v[17];
#pragma unroll
                for (int i = 0; i < 17; ++i) {
                    unsigned u = s1P[i * W1 + tsw];
                    v[i] = sh ? unphi(u) : unplo(u);
                }
                for (int kk = 0; kk < 3; ++kk) {      // <=34 weights live
                    int k = kh * 5 + kk;              // {0,1,2} / {5,6,7}
                    int p = kh * 3 + kk;
                    const float* fR = fhp + k * 136 + fro;   // uniform -> s_load
                    const float* fI = fhp + k * 136 + fio;
                    float cr = 0.f, ci = 0.f;
#pragma unroll
                    for (int i = 0; i < 17; ++i) {
                        cr = fmaf(fR[i], v[i], cr);
                        ci = fmaf(fI[i], v[i], ci);
                    }
                    cbuf[p * CSTR + tsw] = cr;
                    cbuf[p * CSTR + 300 + tsw] = ci;
                }
            }
            int wv = __builtin_amdgcn_readfirstlane(wave);
            if (wv < 6 && lane < 9) {                 // balanced tail t 256..264
                int t = 256 + lane;
                int tsw = t + (t >> 3);
                float v[17];
#pragma unroll
                for (int i = 0; i < 17; ++i) {
                    unsigned u = s1P[i * W1 + tsw];
                    v[i] = sh ? unphi(u) : unplo(u);
                }
                int k = (wv < 3) ? wv : wv + 2;
                const float* fR = fhp + k * 136 + fro;
                const float* fI = fhp + k * 136 + fio;
                float cr = 0.f, ci = 0.f;
#pragma unroll
                for (int i = 0; i < 17; ++i) {
                    cr = fmaf(fR[i], v[i], cr);
                    ci = fmaf(fI[i], v[i], ci);
                }
                cbuf[wv * CSTR + tsw] = cr;
                cbuf[wv * CSTR + 300 + tsw] = ci;
            }
        }
        __syncthreads();

        if (tid < 192) {          // out: 6 plane-sets x 32 X, partners via u±v
            int s = tid >> 5, X = tid & 31;
            int kdist = (s < 3) ? s : s + 2;          // {0,1,2,5,6,7}
            const float* hb = fhp + kdist * 136 + ((X == 0) ? 34 : 0);
            const float* cR = cbuf + s * CSTR + 9 * X;
            float u = 0.f, v2 = 0.f;
#pragma unroll
            for (int j = 0; j < 17; ++j) {
                int off = j + (j >> 3);
                u  = fmaf(hb[j], cR[off], u);
                v2 = fmaf(hb[17 + j], cR[off + 300], v2);
            }
            int g = sh ? gb : ga;
            int ch0 = isimg ? 1 : 11 + g * 10;
            out[nb + (size_t)(ch0 + kdist) * 1024 + Y * 32 + X] = u - v2;
            if (s == 1 || s == 2 || s == 4 || s == 5) {
                int partner = (s < 3) ? 5 - s : 13 - s;   // 4,3,9,8
                out[nb + (size_t)(ch0 + partner) * 1024 + Y * 32 + X] = u + v2;
            }
        } else if (isimg && tid < 224) {              // s0: clipped 7x7 blur
            int X = tid - 192;
            float s0 = 0.f;
#pragma unroll
            for (int p = 0; p < 7; ++p)
#pragma unroll
                for (int q = 0; q < 7; ++q) {
                    int c = 8 * X + q + 5;
                    s0 = fmaf(blur[p * 7 + q],
                              unplo(s1P[(p + 5) * W1 + c + (c >> 3)]), s0);
                }
            out[nb + Y * 32 + X] = s0;
        }
        if (sh + 1 < nsrc) __syncthreads();
    }
}

extern "C" void kernel_launch(void* const* d_in, const int* in_sizes, int n_in,
                              void* d_out, int out_size, void* d_ws, size_t ws_size,
                              hipStream_t stream) {
    const float* img    = (const float*)d_in[0];
    const float* psi_re = (const float*)d_in[1];
    const float* psi_im = (const float*)d_in[2];
    const float* blur   = (const float*)d_in[3];
    float* out = (float*)d_out;
    float* fhp = (float*)d_ws;

    k_fhp<<<22, 64, 0, stream>>>(psi_re, psi_im, blur, fhp);

    dim3 g2(32, 7, 8);
    k_fused6<<<g2, 512, 0, stream>>>(img, psi_re, psi_im, blur, fhp, out);
}

// Round 21
// 50.547 us; speedup vs baseline: 1.0570x; 1.0570x over previous
//
#include <hip/hip_runtime.h>
#include <math.h>

// ---------------------------------------------------------------------------
// ScatteringNetwork — fused, rank-2 composed conv + theta-symmetry
// (R15/R17/R18/R19 base). R21 = R19 (fp32 strip, bf16-packed Iv/s1,
// 3 blocks/CU) + heavy-first block-type order: grid y = {4 pairs, g0, g5,
// img} so the final dispatch round is light blocks (tail trim). R20's strip
// packing reverted (cost VALU, no occupancy gain).
//
// psi_k = F_k (x) H_k (rank-1). theta = pi*k/5 -> H3=H2, F3=conj(F2) (pairs
// (1,4),(2,3),(6,9),(7,8); k0,k5 real-H):
//  - s1 pair blocks: both channels from 4 shared real convs
//  - C: conj-trick -> 6 distinct planes {0,1,2,5,6,7}
//  - out: u=H'r*Cr, v=H'i*Ci -> out_k=u-v, out_partner=u+v
//
// ws: [0) fhp 10*136 floats only.
// fhp per ch: [0)H'r [17)H'i [34)H''r [51)H''i [68)F'r [85)F'i [102)F''r [119)F''i
// ---------------------------------------------------------------------------

#define W1    298            // packed s1 row stride (u32 slots, 17 rows)
#define SSTR  276            // fp32 strip row stride (27 rows, s2 path)
#define IVSTR 300            // packed Iv row stride (u32 slots, 17 rows)
#define CSTR  600            // C fp32 per-plane stride (re@0, im@300), 6 planes

static __device__ __forceinline__ unsigned packbf2(float a, float b) {
    unsigned ua = __float_as_uint(a);
    unsigned ub = __float_as_uint(b);
    ua = (ua + 0x7FFFu + ((ua >> 16) & 1u)) >> 16;          // RNE bf16, lo
    ub = (ub + 0x7FFFu + ((ub >> 16) & 1u)) & 0xFFFF0000u;  // RNE bf16, hi
    return ua | ub;
}
static __device__ __forceinline__ float unplo(unsigned u) { return __uint_as_float(u << 16); }
static __device__ __forceinline__ float unphi(unsigned u) { return __uint_as_float(u & 0xFFFF0000u); }

// ---------------- k_fhp: composed factor table only (tiny) -----------------
__global__ void k_fhp(const float* __restrict__ psi_re,
                      const float* __restrict__ psi_im,
                      const float* __restrict__ blur,
                      float* __restrict__ fhp) {
    int g = blockIdx.x * 64 + threadIdx.x;
    if (g >= 1360) return;
    int ch = g / 136;
    int w = g - ch * 136;
    int part = w / 17;
    int i = w - part * 17;
    const float* pr = psi_re + ch * 121;
    const float* pi = psi_im + ch * 121;
    float val = 0.f;
    if (part < 4) {                       // H-type: H_j = psi[5][j]
        int qmin = (part >= 2) ? 3 : 0;
        int comp = part & 1;
        float bden = blur[24];
        for (int q = qmin; q < 7; ++q) {
            int jj = i - q;
            if (jj < 0 || jj > 10) continue;
            float bq = blur[21 + q] / bden;
            float hh = comp ? pi[55 + jj] : pr[55 + jj];
            val += bq * hh;
        }
    } else {                              // F-type: F_i = psi[i][5]/psi[5][5]
        int pmin = (part >= 6) ? 3 : 0;
        int comp = part & 1;
        float dr = pr[60], di = pi[60];
        float inv = 1.f / (dr * dr + di * di);
        for (int p = pmin; p < 7; ++p) {
            int ii = i - p;
            if (ii < 0 || ii > 10) continue;
            float ap = blur[p * 7 + 3];
            float nr = pr[ii * 11 + 5], ni = pi[ii * 11 + 5];
            float f = comp ? (ni * dr - nr * di) * inv
                           : (nr * dr + ni * di) * inv;
            val += ap * f;
        }
    }
    fhp[g] = val;
}

// ---------------- k_fused5: one block per (Y, stype, n), 512 thr -----------
// stype: 0..3 = pairs (1,4),(2,3),(6,9),(7,8); 4 = g0; 5 = g5; 6 = img.
// Heavy types first so the dispatch tail is light blocks.
__global__ __launch_bounds__(512, 6) void k_fused5(const float* __restrict__ img,
                                                   const float* __restrict__ psi_re,
                                                   const float* __restrict__ psi_im,
                                                   const float* __restrict__ blur,
                                                   const float* __restrict__ fhp,
                                                   float* __restrict__ out) {
    __shared__ __align__(16) float bufA[7452];   // fp32 strip [27][276] / packed s1 [17][298]
    __shared__ __align__(16) float bufB[5100];   // packed Iv [17][300] / C fp32 6*600
    unsigned* s1P = (unsigned*)bufA;
    unsigned* ivP = (unsigned*)bufB;
    const int tid = threadIdx.x;
    const int lane = tid & 63;
    const int wave = tid >> 6;
    const int Y = blockIdx.x;
    const int stype = blockIdx.y;   // 0..3 pairs, 4 g0, 5 g5, 6 img
    const int n = blockIdx.z;
    size_t nb = (size_t)n * 111 * 1024;
    const float* im = img + n * 65536;

    const bool isimg = (stype == 6);
    const bool paired = (stype < 4);
    int ga = 0, gb = 0;
    if (stype == 4) ga = gb = 0;
    else if (stype == 5) ga = gb = 5;
    else if (paired) {
        int p2 = stype;
        ga = (p2 < 2) ? 1 + p2 : 4 + p2;      // 1,2,6,7
        gb = (p2 < 2) ? 4 - p2 : 11 - p2;     // 4,3,9,8
    }

    if (isimg) {
        // stage img strip [17 rows] packed (v,v) into W1 layout, direct from
        // img with predicates (strip col cc = 4c4+e <-> img col cc-8; row
        // gr = 8Y-8+r). cols cc>264 zeroed (alias row r+1 t0..6 slots).
        int rb = 8 * Y - 8;
        for (int idx = tid; idx < 17 * 68; idx += 512) {
            int r = idx / 68, c4 = idx - r * 68;
            int gr = rb + r;
            float4 v = {0.f, 0.f, 0.f, 0.f};
            if (gr >= 0 && gr < 256 && c4 >= 2 && c4 <= 65)
                v = *(const float4*)(im + gr * 256 + 4 * c4 - 8);
            int c = 4 * c4;
            int d = r * W1 + c + (c >> 3);   // (c>>3) constant within a float4
            float vs[4] = {v.x, v.y, v.z, v.w};
#pragma unroll
            for (int e = 0; e < 4; ++e) {
                float val = (c + e > 264) ? 0.f : vs[e];
                s1P[d + e] = packbf2(val, val);
            }
        }
    } else {
        const float* pr = psi_re + ga * 121;   // block-uniform -> s_load
        const float* pi = psi_im + ga * 121;
        float dr = pr[60], di = pi[60];
        float inv = rsqrtf(dr * dr + di * di);

        // stage fp32 strip [27][276]: img rows 8Y-13.., strip col cc = img+8
        int rb2 = 8 * Y - 13;
        for (int idx = tid; idx < 27 * 68; idx += 512) {
            int r = idx / 68, c4 = idx - r * 68;
            int gr = rb2 + r;
            float4 v = {0.f, 0.f, 0.f, 0.f};
            if (gr >= 0 && gr < 256 && c4 >= 2 && c4 <= 65)
                v = *(const float4*)(im + gr * 256 + 4 * c4 - 8);
            *(float4*)(bufA + r * SSTR + 4 * c4) = v;
        }
        __syncthreads();

        // Iv packed (re|im): lane = col v, 8 rows/task (conflict-free reads)
        for (int task = tid; task < 532; task += 512) {
            int rg = (task >= 266) ? 1 : 0;
            int v = task - rg * 266;
            int r0 = rg * 8;
            const float* sp = bufA + r0 * SSTR + v + 3;
            float xv[18];
#pragma unroll
            for (int p = 0; p < 18; ++p) xv[p] = sp[p * SSTR];
            int dsw = v + (v >> 3);
            unsigned* dP = ivP + r0 * IVSTR + dsw;
#pragma unroll
            for (int m = 0; m < 8; ++m) {
                float ar = 0.f, ai = 0.f;
#pragma unroll
                for (int p = 0; p < 11; ++p) {
                    ar = fmaf(pr[p * 11 + 5], xv[m + p], ar);
                    ai = fmaf(pi[p * 11 + 5], xv[m + p], ai);
                }
                dP[m * IVSTR] = packbf2(ar, ai);
            }
        }
        if (tid < 266) {                     // row 16
            int v = tid;
            const float* sp = bufA + 16 * SSTR + v + 3;
            float ar = 0.f, ai = 0.f;
#pragma unroll
            for (int p = 0; p < 11; ++p) {
                float x = sp[p * SSTR];
                ar = fmaf(pr[p * 11 + 5], x, ar);
                ai = fmaf(pi[p * 11 + 5], x, ai);
            }
            ivP[16 * IVSTR + v + (v >> 3)] = packbf2(ar, ai);
        }
        __syncthreads();

        // s1 packed (chanA|chanB): 18 packed reads -> 36 values
        int rowbase = 8 * Y - 8;
        for (int t2 = tid; t2 < 544; t2 += 512) {
            int r = t2 >> 5, xg = t2 & 31;
            int ry = rowbase + r;
            int wb = r * W1 + 9 * xg + 9;
            if (ry >= 0 && ry < 256) {
                const unsigned* sP = ivP + r * IVSTR + 9 * xg;
                float xr[18], xi[18];
#pragma unroll
                for (int j = 0; j < 18; ++j) {
                    unsigned u = sP[j + (j >> 3)];
                    xr[j] = unplo(u);
                    xi[j] = unphi(u);
                }
                if (paired) {
#pragma unroll
                    for (int m = 0; m < 8; ++m) {
                        float a = 0.f, b = 0.f, c = 0.f, d = 0.f;
#pragma unroll
                        for (int j = 0; j < 11; ++j) {
                            float hr = pr[55 + j], hi2 = pi[55 + j];
                            a = fmaf(hr, xr[m + j], a);
                            b = fmaf(hi2, xi[m + j], b);
                            c = fmaf(hr, xi[m + j], c);
                            d = fmaf(hi2, xr[m + j], d);
                        }
                        float e1 = a - b, o1 = c + d;
                        float e2 = a + b, o2 = c - d;
                        s1P[wb + m] = packbf2(inv * sqrtf(fmaf(e1, e1, o1 * o1)),
                                              inv * sqrtf(fmaf(e2, e2, o2 * o2)));
                    }
                } else {
#pragma unroll
                    for (int m = 0; m < 8; ++m) {
                        float sr = 0.f, si = 0.f;
#pragma unroll
                        for (int j = 0; j < 11; ++j) {
                            float hr = pr[55 + j], hi2 = pi[55 + j];
                            sr = fmaf(hr, xr[m + j], fmaf(-hi2, xi[m + j], sr));
                            si = fmaf(hr, xi[m + j], fmaf(hi2, xr[m + j], si));
                        }
                        float val = inv * sqrtf(fmaf(sr, sr, si * si));
                        s1P[wb + m] = packbf2(val, val);
                    }
                }
            } else {
#pragma unroll
                for (int m = 0; m < 8; ++m) s1P[wb + m] = 0u;
            }
        }
        if (tid < 17) {                      // edge zeros: t 0..7 and t 264 slot
            int r = tid;
#pragma unroll
            for (int t = 0; t < 8; ++t) s1P[r * W1 + t] = 0u;
            s1P[r * W1 + 297] = 0u;
        }
    }
    __syncthreads();

    // ---- per-source: C (6 planes fp32, overwrites Iv) then out ----
    const int nsrc = paired ? 2 : 1;
    for (int sh = 0; sh < nsrc; ++sh) {
        {
            int kh = __builtin_amdgcn_readfirstlane(wave >> 2);   // plane half
            int wl = wave & 3;
            int fro = (Y == 0) ? 102 : 68;
            int fio = (Y == 0) ? 119 : 85;
            {   // main pass: t 0..255
                int t = (wl << 6) + lane;
                int tsw = t + (t >> 3);
                float v[17];
#pragma unroll
                for (int i = 0; i < 17; ++i) {
                    unsigned u = s1P[i * W1 + tsw];
                    v[i] = sh ? unphi(u) : unplo(u);
                }
                for (int kk = 0; kk < 3; ++kk) {      // <=34 weights live
                    int k = kh * 5 + kk;              // {0,1,2} / {5,6,7}
                    int p = kh * 3 + kk;
                    const float* fR = fhp + k * 136 + fro;   // uniform -> s_load
                    const float* fI = fhp + k * 136 + fio;
                    float cr = 0.f, ci = 0.f;
#pragma unroll
                    for (int i = 0; i < 17; ++i) {
                        cr = fmaf(fR[i], v[i], cr);
                        ci = fmaf(fI[i], v[i], ci);
                    }
                    bufB[p * CSTR + tsw] = cr;
                    bufB[p * CSTR + 300 + tsw] = ci;
                }
            }
            int wv = __builtin_amdgcn_readfirstlane(wave);
            if (wv < 6 && lane < 9) {                 // balanced tail t 256..264
                int t = 256 + lane;
                int tsw = t + (t >> 3);
                float v[17];
#pragma unroll
                for (int i = 0; i < 17; ++i) {
                    unsigned u = s1P[i * W1 + tsw];
                    v[i] = sh ? unphi(u) : unplo(u);
                }
                int k = (wv < 3) ? wv : wv + 2;
                const float* fR = fhp + k * 136 + fro;
                const float* fI = fhp + k * 136 + fio;
                float cr = 0.f, ci = 0.f;
#pragma unroll
                for (int i = 0; i < 17; ++i) {
                    cr = fmaf(fR[i], v[i], cr);
                    ci = fmaf(fI[i], v[i], ci);
                }
                bufB[wv * CSTR + tsw] = cr;
                bufB[wv * CSTR + 300 + tsw] = ci;
            }
        }
        __syncthreads();

        if (tid < 192) {          // out: 6 plane-sets x 32 X, partners via u±v
            int s = tid >> 5, X = tid & 31;
            int kdist = (s < 3) ? s : s + 2;          // {0,1,2,5,6,7}
            const float* hb = fhp + kdist * 136 + ((X == 0) ? 34 : 0);
            const float* cR = bufB + s * CSTR + 9 * X;
            float u = 0.f, v2 = 0.f;
#pragma unroll
            for (int j = 0; j < 17; ++j) {
                int off = j + (j >> 3);
                u  = fmaf(hb[j], cR[off], u);
                v2 = fmaf(hb[17 + j], cR[off + 300], v2);
            }
            int g = sh ? gb : ga;
            int ch0 = isimg ? 1 : 11 + g * 10;
            out[nb + (size_t)(ch0 + kdist) * 1024 + Y * 32 + X] = u - v2;
            if (s == 1 || s == 2 || s == 4 || s == 5) {
                int partner = (s < 3) ? 5 - s : 13 - s;   // 4,3,9,8
                out[nb + (size_t)(ch0 + partner) * 1024 + Y * 32 + X] = u + v2;
            }
        } else if (isimg && tid < 224) {              // s0: clipped 7x7 blur
            int X = tid - 192;
            float s0 = 0.f;
#pragma unroll
            for (int p = 0; p < 7; ++p)
#pragma unroll
                for (int q = 0; q < 7; ++q) {
                    int c = 8 * X + q + 5;
                    s0 = fmaf(blur[p * 7 + q],
                              unplo(s1P[(p + 5) * W1 + c + (c >> 3)]), s0);
                }
            out[nb + Y * 32 + X] = s0;
        }
        if (sh + 1 < nsrc) __syncthreads();
    }
}

extern "C" void kernel_launch(void* const* d_in, const int* in_sizes, int n_in,
                              void* d_out, int out_size, void* d_ws, size_t ws_size,
                              hipStream_t stream) {
    const float* img    = (const float*)d_in[0];
    const float* psi_re = (const float*)d_in[1];
    const float* psi_im = (const float*)d_in[2];
    const float* blur   = (const float*)d_in[3];
    float* out = (float*)d_out;
    float* fhp = (float*)d_ws;

    k_fhp<<<22, 64, 0, stream>>>(psi_re, psi_im, blur, fhp);

    dim3 g2(32, 7, 8);
    k_fused5<<<g2, 512, 0, stream>>>(img, psi_re, psi_im, blur, fhp, out);
}